// Round 1
// baseline (66.336 us; speedup 1.0000x reference)
//
#include <hip/hip_runtime.h>
#include <math.h>

#define B_ 16
#define N_ 18
#define H_ 256
#define W_ 256
#define K_ 64
#define HW_ (H_ * W_)
#define NPTS 36
#define NPAIR 630            // 36*35/2
#define EPS_F 1.1920928955078125e-07f   // np.finfo(float32).eps

__device__ __forceinline__ float shoelace4(const float* x, const float* y) {
    float s = 0.f;
#pragma unroll
    for (int i = 0; i < 4; ++i) {
        int j = (i + 1) & 3;
        s += x[i] * y[j] - y[i] * x[j];
    }
    return 0.5f * fabsf(s);
}

__global__ __launch_bounds__(64) void iou_row_kernel(
    const float* __restrict__ output, const int* __restrict__ mask,
    const int* __restrict__ ind, const float* __restrict__ target,
    float* __restrict__ rowSl1, float* __restrict__ rowLi)
{
    const int row = blockIdx.x;          // 0 .. B*K-1
    const int b   = row >> 6;            // K_ = 64
    const int tid = threadIdx.x;

    __shared__ float ptsx[2][NPTS], ptsy[2][NPTS];   // [0]=pred poly, [1]=target poly
    __shared__ float cX[2][4], cY[2][4];             // sorted rect corners
    __shared__ float terms[N_];
    __shared__ float s_sl1;

    const int idx = ind[row];

    if (tid < N_) {
        float p = output[(size_t)(b * N_ + tid) * HW_ + idx];
        float t = target[row * N_ + tid];
        float d = p - t;
        float ad = fabsf(d);
        terms[tid] = (ad < 1.f) ? 0.5f * d * d : (ad - 0.5f);
        float ang = (float)tid * ((float)M_PI / 18.0f);
        float c = cosf(ang), s = sinf(ang);
        float px = p * c, py = p * s;
        ptsx[0][tid]      =  px;  ptsy[0][tid]      =  py;
        ptsx[0][tid + 18] = -px;  ptsy[0][tid + 18] = -py;
        float tx = t * c, ty = t * s;
        ptsx[1][tid]      =  tx;  ptsy[1][tid]      =  ty;
        ptsx[1][tid + 18] = -tx;  ptsy[1][tid + 18] = -ty;
    }
    __syncthreads();
    if (tid == 0) {
        float s = 0.f;
        for (int i = 0; i < N_; ++i) s += terms[i];
        s_sl1 = s / (float)N_;
    }

    // --- min-area rect for both polygons ---
    for (int poly = 0; poly < 2; ++poly) {
        const float* PX = ptsx[poly];
        const float* PY = ptsy[poly];

        float bestA = INFINITY;
        int   bestM = 0x7fffffff;
        for (int m = tid; m < NPAIR; m += 64) {
            int i = 0, rem = m;
            while (rem >= 35 - i) { rem -= 35 - i; ++i; }
            int j = i + 1 + rem;
            float dx = PX[j] - PX[i], dy = PY[j] - PY[i];
            float nrm = sqrtf(dx * dx + dy * dy);
            float inv = 1.f / fmaxf(nrm, 1e-9f);
            float ux = dx * inv, uy = dy * inv;
            float vx = -uy, vy = ux;
            float umin = INFINITY, umax = -INFINITY;
            float vmin = INFINITY, vmax = -INFINITY;
#pragma unroll 4
            for (int kk = 0; kk < NPTS; ++kk) {
                float x = PX[kk], y = PY[kk];
                float pu = ux * x + uy * y;
                float pv = vx * x + vy * y;
                umin = fminf(umin, pu); umax = fmaxf(umax, pu);
                vmin = fminf(vmin, pv); vmax = fmaxf(vmax, pv);
            }
            float area = (nrm > 1e-9f) ? (umax - umin) * (vmax - vmin) : INFINITY;
            if (area < bestA) { bestA = area; bestM = m; }
        }
        // wave argmin, first-index tie-break (lexicographic on (area, m))
        for (int off = 32; off > 0; off >>= 1) {
            float oa = __shfl_down(bestA, off, 64);
            int   om = __shfl_down(bestM, off, 64);
            if (oa < bestA || (oa == bestA && om < bestM)) { bestA = oa; bestM = om; }
        }
        if (tid == 0) {
            int m = bestM;
            int i = 0, rem = m;
            while (rem >= 35 - i) { rem -= 35 - i; ++i; }
            int j = i + 1 + rem;
            float dx = PX[j] - PX[i], dy = PY[j] - PY[i];
            float nrm = sqrtf(dx * dx + dy * dy);
            float inv = 1.f / fmaxf(nrm, 1e-9f);
            float ux = dx * inv, uy = dy * inv;
            float vx = -uy, vy = ux;
            float umin = INFINITY, umax = -INFINITY;
            float vmin = INFINITY, vmax = -INFINITY;
            for (int kk = 0; kk < NPTS; ++kk) {
                float x = PX[kk], y = PY[kk];
                float pu = ux * x + uy * y;
                float pv = vx * x + vy * y;
                umin = fminf(umin, pu); umax = fmaxf(umax, pu);
                vmin = fminf(vmin, pv); vmax = fmaxf(vmax, pv);
            }
            float cu[4] = { umin, umax, umax, umin };
            float cv[4] = { vmin, vmin, vmax, vmax };
            float cx[4], cy[4], angq[4];
#pragma unroll
            for (int q = 0; q < 4; ++q) {
                cx[q] = cu[q] * ux + cv[q] * vx;
                cy[q] = cu[q] * uy + cv[q] * vy;
                angq[q] = atan2f(cy[q], cx[q]);
            }
            // stable insertion sort by angle ascending
            int ord[4] = { 0, 1, 2, 3 };
            for (int a = 1; a < 4; ++a) {
                int key = ord[a]; float ka = angq[key]; int bb = a - 1;
                while (bb >= 0 && angq[ord[bb]] > ka) { ord[bb + 1] = ord[bb]; --bb; }
                ord[bb + 1] = key;
            }
#pragma unroll
            for (int q = 0; q < 4; ++q) { cX[poly][q] = cx[ord[q]]; cY[poly][q] = cy[ord[q]]; }
        }
        __syncthreads();
    }

    // --- polygon IoU + losses (serial on lane 0; tiny) ---
    if (tid == 0) {
        float areaA = shoelace4(cX[0], cY[0]);
        float areaB = shoelace4(cX[1], cY[1]);

        float px_[16], py_[16], qx_[16], qy_[16];
        int cnt = 4;
#pragma unroll
        for (int q = 0; q < 4; ++q) { px_[q] = cX[0][q]; py_[q] = cY[0][q]; }

        for (int e = 0; e < 4 && cnt > 0; ++e) {
            float e1x = cX[1][e],           e1y = cY[1][e];
            float e2x = cX[1][(e + 1) & 3], e2y = cY[1][(e + 1) & 3];
            float dex = e2x - e1x, dey = e2y - e1y;
            int m2 = 0;
            for (int q2 = 0; q2 < cnt; ++q2) {
                int qn = (q2 + 1 == cnt) ? 0 : q2 + 1;
                float cxv = px_[q2], cyv = py_[q2];
                float nxv = px_[qn], nyv = py_[qn];
                float sc = dex * (cyv - e1y) - dey * (cxv - e1x);
                float sn = dex * (nyv - e1y) - dey * (nxv - e1x);
                bool s_in = (sc >= 0.f), e_in = (sn >= 0.f);
                if (s_in != e_in && m2 < 16) {
                    float denom = sc - sn;
                    if (fabsf(denom) < 1e-12f) denom = 1e-12f;   // match reference clamp
                    float tt = sc / denom;
                    qx_[m2] = cxv + tt * (nxv - cxv);
                    qy_[m2] = cyv + tt * (nyv - cyv);
                    ++m2;
                }
                if (e_in && m2 < 16) { qx_[m2] = nxv; qy_[m2] = nyv; ++m2; }
            }
            cnt = m2;
            for (int q2 = 0; q2 < cnt; ++q2) { px_[q2] = qx_[q2]; py_[q2] = qy_[q2]; }
        }

        float inter = 0.f;
        if (cnt >= 3) {
            float s = 0.f;
            for (int q2 = 0; q2 < cnt; ++q2) {
                int qn = (q2 + 1 == cnt) ? 0 : q2 + 1;
                s += px_[q2] * py_[qn] - py_[q2] * px_[qn];
            }
            inter = 0.5f * fabsf(s);
        }
        float uni = areaA + areaB - inter;
        float iou = inter / fmaxf(uni, 1e-12f);

        float sl1 = s_sl1;
        float mf = (float)mask[row];
        float alpha = -logf(fabsf(iou) + EPS_F);
        float li = alpha * sl1 / (fabsf(sl1) + EPS_F);
        rowSl1[row] = sl1 * mf;
        rowLi[row]  = li * mf;
    }
}

__global__ __launch_bounds__(256) void iou_reduce_kernel(
    const float* __restrict__ rowSl1, const float* __restrict__ rowLi,
    const int* __restrict__ mask, float* __restrict__ out)
{
    __shared__ float s1[256], s2[256], s3[256];
    const int tid = threadIdx.x;
    float a = 0.f, c = 0.f, msum = 0.f;
    for (int i = tid; i < B_ * K_; i += 256) {
        a += rowSl1[i];
        c += rowLi[i];
        msum += (float)mask[i];
    }
    s1[tid] = a; s2[tid] = c; s3[tid] = msum;
    __syncthreads();
    for (int off = 128; off > 0; off >>= 1) {
        if (tid < off) {
            s1[tid] += s1[tid + off];
            s2[tid] += s2[tid + off];
            s3[tid] += s3[tid + off];
        }
        __syncthreads();
    }
    if (tid == 0) {
        float cnt = fmaxf(s3[0], 1.0f);
        out[0] = s1[0] / cnt;
        out[1] = s2[0] / cnt;
    }
}

extern "C" void kernel_launch(void* const* d_in, const int* in_sizes, int n_in,
                              void* d_out, int out_size, void* d_ws, size_t ws_size,
                              hipStream_t stream) {
    const float* output = (const float*)d_in[0];
    const int*   mask   = (const int*)d_in[1];
    const int*   ind    = (const int*)d_in[2];
    const float* target = (const float*)d_in[3];
    float* out    = (float*)d_out;
    float* rowSl1 = (float*)d_ws;
    float* rowLi  = rowSl1 + B_ * K_;

    iou_row_kernel<<<B_ * K_, 64, 0, stream>>>(output, mask, ind, target, rowSl1, rowLi);
    iou_reduce_kernel<<<1, 256, 0, stream>>>(rowSl1, rowLi, mask, out);
}

// Round 2
// 37.881 us; speedup vs baseline: 1.7512x; 1.7512x over previous
//
#include <hip/hip_runtime.h>
#include <math.h>

#define B_ 16
#define N_ 18
#define HW_ 65536
#define K_ 64
#define NPAIR 630            // 36*35/2
#define EPS_F 1.1920928955078125e-07f   // np.finfo(float32).eps

// decode pair index m in [0,630) -> (i,j), i<j<36, row-major triu order
__device__ __forceinline__ void decode_pair(int m, int& pi, int& pj) {
    int i = (int)((71.0f - sqrtf(5041.0f - 8.0f * (float)m)) * 0.5f);
    i = max(0, min(34, i));
    // S(i) = i*(71-i)/2 = number of pairs with first index < i
    while (i > 0 && m < i * (71 - i) / 2) --i;
    while (i < 34 && m >= (i + 1) * (70 - i) / 2) ++i;
    pi = i;
    pj = m - i * (71 - i) / 2 + i + 1;
}

__device__ __forceinline__ float shoelace4(const float* x, const float* y) {
    float s = 0.f;
#pragma unroll
    for (int i = 0; i < 4; ++i) {
        int j = (i + 1) & 3;
        s += x[i] * y[j] - y[i] * x[j];
    }
    return 0.5f * fabsf(s);
}

__global__ __launch_bounds__(256) void iou_row_kernel(
    const float* __restrict__ output, const int* __restrict__ mask,
    const int* __restrict__ ind, const float* __restrict__ target,
    float* __restrict__ rowSl1, float* __restrict__ rowLi)
{
    const int row = blockIdx.x;          // 0 .. B*K-1
    const int b   = row >> 6;            // K_ = 64
    const int tid = threadIdx.x;

    __shared__ float ptsx[2][36], ptsy[2][36];   // [0]=pred poly, [1]=target poly
    __shared__ float cX[2][4], cY[2][4];         // sorted rect corners
    __shared__ float terms[N_];
    __shared__ float s_sl1;
    __shared__ unsigned long long wred[4];       // per-wave argmin results

    const int idx = ind[row];

    if (tid < N_) {
        float p = output[(size_t)(b * N_ + tid) * HW_ + idx];
        float t = target[row * N_ + tid];
        float d = p - t;
        float ad = fabsf(d);
        terms[tid] = (ad < 1.f) ? 0.5f * d * d : (ad - 0.5f);
        float ang = (float)tid * ((float)M_PI / 18.0f);
        float c = cosf(ang), s = sinf(ang);
        float px = p * c, py = p * s;
        ptsx[0][tid]      =  px;  ptsy[0][tid]      =  py;
        ptsx[0][tid + 18] = -px;  ptsy[0][tid + 18] = -py;
        float tx = t * c, ty = t * s;
        ptsx[1][tid]      =  tx;  ptsy[1][tid]      =  ty;
        ptsx[1][tid + 18] = -tx;  ptsy[1][tid + 18] = -ty;
    }
    __syncthreads();

    // --- pair phase: threads 0-127 -> poly 0, threads 128-255 -> poly 1 ---
    {
        const int poly = tid >> 7;
        const int l    = tid & 127;
        const float* PX = ptsx[poly];
        const float* PY = ptsy[poly];
        unsigned long long best = 0xFFFFFFFFFFFFFFFFULL;
        for (int m = l; m < NPAIR; m += 128) {
            int i, j; decode_pair(m, i, j);
            float dx = PX[j] - PX[i], dy = PY[j] - PY[i];
            float nrm = sqrtf(dx * dx + dy * dy);
            float inv = 1.f / fmaxf(nrm, 1e-9f);
            float ux = dx * inv, uy = dy * inv;
            float vx = -uy, vy = ux;
            // pts[k+18] = -pts[k] exactly -> umin = -umax, vmin = -vmax
            float pmin = INFINITY, pmax = -INFINITY;
            float qmin = INFINITY, qmax = -INFINITY;
#pragma unroll 6
            for (int kk = 0; kk < 18; ++kk) {
                float x = PX[kk], y = PY[kk];
                float pu = ux * x + uy * y;
                float pv = vx * x + vy * y;
                pmin = fminf(pmin, pu); pmax = fmaxf(pmax, pu);
                qmin = fminf(qmin, pv); qmax = fmaxf(qmax, pv);
            }
            float umax = fmaxf(pmax, -pmin);
            float vmax = fmaxf(qmax, -qmin);
            float area = (umax + umax) * (vmax + vmax);   // == (umax-umin)*(vmax-vmin)
            area = (nrm > 1e-9f) ? area : INFINITY;
            unsigned long long key =
                ((unsigned long long)__float_as_uint(area) << 32) | (unsigned)m;
            if (key < best) best = key;
        }
        // wave argmin (lexicographic (area, m) via packed key)
        for (int off = 32; off > 0; off >>= 1) {
            unsigned long long o = __shfl_down(best, off, 64);
            if (o < best) best = o;
        }
        if ((tid & 63) == 0) wred[tid >> 6] = best;
    }
    __syncthreads();

    // --- tails in parallel: t0 -> rect poly0, t128 -> rect poly1, t64 -> sl1 ---
    if (tid == 64) {
        float s = 0.f;
        for (int i2 = 0; i2 < N_; ++i2) s += terms[i2];
        s_sl1 = s / (float)N_;
    }
    if ((tid & 127) == 0) {
        const int poly = tid >> 7;
        const float* PX = ptsx[poly];
        const float* PY = ptsy[poly];
        unsigned long long b0 = wred[2 * poly], b1 = wred[2 * poly + 1];
        unsigned long long bb = (b1 < b0) ? b1 : b0;
        int m = (int)(bb & 0xFFFFFFFFULL);
        int i, j; decode_pair(m, i, j);
        float dx = PX[j] - PX[i], dy = PY[j] - PY[i];
        float nrm = sqrtf(dx * dx + dy * dy);
        float inv = 1.f / fmaxf(nrm, 1e-9f);
        float ux = dx * inv, uy = dy * inv;
        float vx = -uy, vy = ux;
        float pmin = INFINITY, pmax = -INFINITY;
        float qmin = INFINITY, qmax = -INFINITY;
        for (int kk = 0; kk < 18; ++kk) {
            float x = PX[kk], y = PY[kk];
            float pu = ux * x + uy * y;
            float pv = vx * x + vy * y;
            pmin = fminf(pmin, pu); pmax = fmaxf(pmax, pu);
            qmin = fminf(qmin, pv); qmax = fmaxf(qmax, pv);
        }
        float umax = fmaxf(pmax, -pmin), umin = -umax;
        float vmax = fmaxf(qmax, -qmin), vmin = -vmax;
        float cu[4] = { umin, umax, umax, umin };
        float cv[4] = { vmin, vmin, vmax, vmax };
        float cx[4], cy[4], angq[4];
#pragma unroll
        for (int q = 0; q < 4; ++q) {
            cx[q] = cu[q] * ux + cv[q] * vx;
            cy[q] = cu[q] * uy + cv[q] * vy;
            angq[q] = atan2f(cy[q], cx[q]);
        }
        // stable insertion sort by angle ascending
        int ord[4] = { 0, 1, 2, 3 };
        for (int a = 1; a < 4; ++a) {
            int key = ord[a]; float ka = angq[key]; int bb2 = a - 1;
            while (bb2 >= 0 && angq[ord[bb2]] > ka) { ord[bb2 + 1] = ord[bb2]; --bb2; }
            ord[bb2 + 1] = key;
        }
#pragma unroll
        for (int q = 0; q < 4; ++q) { cX[poly][q] = cx[ord[q]]; cY[poly][q] = cy[ord[q]]; }
    }
    __syncthreads();

    // --- polygon IoU + losses (serial on thread 0; tiny) ---
    if (tid == 0) {
        float areaA = shoelace4(cX[0], cY[0]);
        float areaB = shoelace4(cX[1], cY[1]);

        float px_[16], py_[16], qx_[16], qy_[16];
        int cnt = 4;
#pragma unroll
        for (int q = 0; q < 4; ++q) { px_[q] = cX[0][q]; py_[q] = cY[0][q]; }

        for (int e = 0; e < 4 && cnt > 0; ++e) {
            float e1x = cX[1][e],           e1y = cY[1][e];
            float e2x = cX[1][(e + 1) & 3], e2y = cY[1][(e + 1) & 3];
            float dex = e2x - e1x, dey = e2y - e1y;
            int m2 = 0;
            for (int q2 = 0; q2 < cnt; ++q2) {
                int qn = (q2 + 1 == cnt) ? 0 : q2 + 1;
                float cxv = px_[q2], cyv = py_[q2];
                float nxv = px_[qn], nyv = py_[qn];
                float sc = dex * (cyv - e1y) - dey * (cxv - e1x);
                float sn = dex * (nyv - e1y) - dey * (nxv - e1x);
                bool s_in = (sc >= 0.f), e_in = (sn >= 0.f);
                if (s_in != e_in && m2 < 16) {
                    float denom = sc - sn;
                    if (fabsf(denom) < 1e-12f) denom = 1e-12f;   // match reference clamp
                    float tt = sc / denom;
                    qx_[m2] = cxv + tt * (nxv - cxv);
                    qy_[m2] = cyv + tt * (nyv - cyv);
                    ++m2;
                }
                if (e_in && m2 < 16) { qx_[m2] = nxv; qy_[m2] = nyv; ++m2; }
            }
            cnt = m2;
            for (int q2 = 0; q2 < cnt; ++q2) { px_[q2] = qx_[q2]; py_[q2] = qy_[q2]; }
        }

        float inter = 0.f;
        if (cnt >= 3) {
            float s = 0.f;
            for (int q2 = 0; q2 < cnt; ++q2) {
                int qn = (q2 + 1 == cnt) ? 0 : q2 + 1;
                s += px_[q2] * py_[qn] - py_[q2] * px_[qn];
            }
            inter = 0.5f * fabsf(s);
        }
        float uni = areaA + areaB - inter;
        float iou = inter / fmaxf(uni, 1e-12f);

        float sl1 = s_sl1;
        float mf = (float)mask[row];
        float alpha = -logf(fabsf(iou) + EPS_F);
        float li = alpha * sl1 / (fabsf(sl1) + EPS_F);
        rowSl1[row] = sl1 * mf;
        rowLi[row]  = li * mf;
    }
}

__global__ __launch_bounds__(256) void iou_reduce_kernel(
    const float* __restrict__ rowSl1, const float* __restrict__ rowLi,
    const int* __restrict__ mask, float* __restrict__ out)
{
    __shared__ float s1[256], s2[256], s3[256];
    const int tid = threadIdx.x;
    float a = 0.f, c = 0.f, msum = 0.f;
    for (int i = tid; i < B_ * K_; i += 256) {
        a += rowSl1[i];
        c += rowLi[i];
        msum += (float)mask[i];
    }
    s1[tid] = a; s2[tid] = c; s3[tid] = msum;
    __syncthreads();
    for (int off = 128; off > 0; off >>= 1) {
        if (tid < off) {
            s1[tid] += s1[tid + off];
            s2[tid] += s2[tid + off];
            s3[tid] += s3[tid + off];
        }
        __syncthreads();
    }
    if (tid == 0) {
        float cnt = fmaxf(s3[0], 1.0f);
        out[0] = s1[0] / cnt;
        out[1] = s2[0] / cnt;
    }
}

extern "C" void kernel_launch(void* const* d_in, const int* in_sizes, int n_in,
                              void* d_out, int out_size, void* d_ws, size_t ws_size,
                              hipStream_t stream) {
    const float* output = (const float*)d_in[0];
    const int*   mask   = (const int*)d_in[1];
    const int*   ind    = (const int*)d_in[2];
    const float* target = (const float*)d_in[3];
    float* out    = (float*)d_out;
    float* rowSl1 = (float*)d_ws;
    float* rowLi  = rowSl1 + B_ * K_;

    iou_row_kernel<<<B_ * K_, 256, 0, stream>>>(output, mask, ind, target, rowSl1, rowLi);
    iou_reduce_kernel<<<1, 256, 0, stream>>>(rowSl1, rowLi, mask, out);
}

// Round 3
// 30.732 us; speedup vs baseline: 2.1586x; 1.2326x over previous
//
#include <hip/hip_runtime.h>
#include <math.h>

#define NPAIR 630
#define EPS_F 1.1920928955078125e-07f   // np.finfo(float32).eps

// decode pair index m in [0,630) -> (i,j), i<j<36, row-major triu order
__device__ __forceinline__ void decode_pair(int m, int& pi, int& pj) {
    int i = (int)((71.0f - sqrtf(5041.0f - 8.0f * (float)m)) * 0.5f);
    i = max(0, min(34, i));
    while (i > 0 && m < i * (71 - i) / 2) --i;
    while (i < 34 && m >= (i + 1) * (70 - i) / 2) ++i;
    pi = i;
    pj = m - i * (71 - i) / 2 + i + 1;
}

// pts[i] for i in [0,36): lanes 0-17 hold base coords; i>=18 is exact negation
__device__ __forceinline__ float fetch_pt(float v, int i) {
    int ii = (i < 18) ? i : (i - 18);
    float r = __shfl(v, ii, 64);
    return (i < 18) ? r : -r;
}

__device__ __forceinline__ float shoe4(float X0,float Y0,float X1,float Y1,
                                       float X2,float Y2,float X3,float Y3) {
    float s = 0.f;
    s += X0 * Y1 - Y0 * X1;
    s += X1 * Y2 - Y1 * X2;
    s += X2 * Y3 - Y2 * X3;
    s += X3 * Y0 - Y3 * X0;
    return 0.5f * fabsf(s);
}

// min-area rect of the 36-pt symmetric polygon whose base coords (lanes 0-17)
// are (xv,yv). All lanes return the angle-sorted corners.
__device__ __forceinline__ void min_area_rect(
    float xv, float yv, int lane,
    float& c0x, float& c0y, float& c1x, float& c1y,
    float& c2x, float& c2y, float& c3x, float& c3y)
{
    float PX[18], PY[18];
#pragma unroll
    for (int k = 0; k < 18; ++k) {
        PX[k] = __shfl(xv, k, 64);
        PY[k] = __shfl(yv, k, 64);
    }

    unsigned long long best = ~0ULL;
#pragma unroll 2
    for (int it = 0; it < 10; ++it) {
        int m = lane + (it << 6);
        if (m < NPAIR) {
            int i, j; decode_pair(m, i, j);
            float xi = fetch_pt(xv, i), yi = fetch_pt(yv, i);
            float xj = fetch_pt(xv, j), yj = fetch_pt(yv, j);
            float dx = xj - xi, dy = yj - yi;
            float nrm = sqrtf(dx * dx + dy * dy);
            float inv = 1.f / fmaxf(nrm, 1e-9f);
            float ux = dx * inv, uy = dy * inv;
            float vx = -uy, vy = ux;
            // pts[k+18] = -pts[k] exactly -> umin=-umax, vmin=-vmax
            float pmin = INFINITY, pmax = -INFINITY;
            float qmin = INFINITY, qmax = -INFINITY;
#pragma unroll
            for (int kk = 0; kk < 18; ++kk) {
                float x = PX[kk], y = PY[kk];
                float pu = ux * x + uy * y;
                float pv = vx * x + vy * y;
                pmin = fminf(pmin, pu); pmax = fmaxf(pmax, pu);
                qmin = fminf(qmin, pv); qmax = fmaxf(qmax, pv);
            }
            float umax = fmaxf(pmax, -pmin);
            float vmax = fmaxf(qmax, -qmin);
            float area = (umax + umax) * (vmax + vmax);
            area = (nrm > 1e-9f) ? area : INFINITY;
            unsigned long long key =
                ((unsigned long long)__float_as_uint(area) << 32) | (unsigned)m;
            if (key < best) best = key;
        }
    }
#pragma unroll
    for (int off = 1; off < 64; off <<= 1) {
        unsigned long long o = __shfl_xor(best, off, 64);
        if (o < best) best = o;
    }

    // redundant finalize on every lane (uniform, divergence-free)
    int m = (int)(best & 0xFFFFFFFFULL);
    int i, j; decode_pair(m, i, j);
    float xi = fetch_pt(xv, i), yi = fetch_pt(yv, i);
    float xj = fetch_pt(xv, j), yj = fetch_pt(yv, j);
    float dx = xj - xi, dy = yj - yi;
    float nrm = sqrtf(dx * dx + dy * dy);
    float inv = 1.f / fmaxf(nrm, 1e-9f);
    float ux = dx * inv, uy = dy * inv;
    float vx = -uy, vy = ux;
    float pmin = INFINITY, pmax = -INFINITY, qmin = INFINITY, qmax = -INFINITY;
#pragma unroll
    for (int kk = 0; kk < 18; ++kk) {
        float x = PX[kk], y = PY[kk];
        float pu = ux * x + uy * y;
        float pv = vx * x + vy * y;
        pmin = fminf(pmin, pu); pmax = fmaxf(pmax, pu);
        qmin = fminf(qmin, pv); qmax = fmaxf(qmax, pv);
    }
    float umax = fmaxf(pmax, -pmin), umin = -umax;
    float vmax = fmaxf(qmax, -qmin), vmin = -vmax;
    float cu0 = umin, cu1 = umax, cu2 = umax, cu3 = umin;
    float cv0 = vmin, cv1 = vmin, cv2 = vmax, cv3 = vmax;
    float x0 = cu0 * ux + cv0 * vx, y0 = cu0 * uy + cv0 * vy;
    float x1 = cu1 * ux + cv1 * vx, y1 = cu1 * uy + cv1 * vy;
    float x2 = cu2 * ux + cv2 * vx, y2 = cu2 * uy + cv2 * vy;
    float x3 = cu3 * ux + cv3 * vx, y3 = cu3 * uy + cv3 * vy;
    float a0 = atan2f(y0, x0), a1 = atan2f(y1, x1);
    float a2 = atan2f(y2, x2), a3 = atan2f(y3, x3);
    int q0 = 0, q1 = 1, q2 = 2, q3 = 3;
    // stable sort-by-angle: lexicographic (ang, orig idx) sorting network
#define CSWP(aA,qA,xA,yA, aB,qB,xB,yB) \
    { bool sw = (aA > aB) || (aA == aB && qA > qB); \
      if (sw) { float tf; int ti; \
        tf = aA; aA = aB; aB = tf;  ti = qA; qA = qB; qB = ti; \
        tf = xA; xA = xB; xB = tf;  tf = yA; yA = yB; yB = tf; } }
    CSWP(a0,q0,x0,y0, a1,q1,x1,y1)
    CSWP(a2,q2,x2,y2, a3,q3,x3,y3)
    CSWP(a0,q0,x0,y0, a2,q2,x2,y2)
    CSWP(a1,q1,x1,y1, a3,q3,x3,y3)
    CSWP(a1,q1,x1,y1, a2,q2,x2,y2)
#undef CSWP
    c0x = x0; c0y = y0; c1x = x1; c1y = y1;
    c2x = x2; c2y = y2; c3x = x3; c3y = y3;
}

// one Sutherland-Hodgman step, literal lane-parallel copy of _clip_halfplane:
// lane j = slot j; input poly in lanes [0,K), output in lanes [0,2K)
template <int K>
__device__ __forceinline__ void clip_step(float& x, float& y,
    float e1x, float e1y, float e2x, float e2y, int lane)
{
    const float dex = e2x - e1x, dey = e2y - e1y;
    float side = dex * (y - e1y) - dey * (x - e1x);
    int nl = (lane + 1) % K;
    float xn = __shfl(x, nl, 64);
    float yn = __shfl(y, nl, 64);
    float siden = __shfl(side, nl, 64);
    float denom = side - siden;
    float dd = (fabsf(denom) < 1e-12f) ? 1e-12f : denom;
    float t = side / dd;
    float ix = x + t * (xn - x);
    float iy = y + t * (yn - y);
    bool s_in = side >= 0.f, e_in = siden >= 0.f;
    int flags = (s_in ? 1 : 0) | (e_in ? 2 : 0);
    // expand: out[2i]=inter[i], out[2i+1]=nxt[i]
    int src = lane >> 1;
    float ex  = __shfl(ix, src, 64);
    float ey  = __shfl(iy, src, 64);
    float nx2 = __shfl(xn, src, 64);
    float ny2 = __shfl(yn, src, 64);
    int   f2  = __shfl(flags, src, 64);
    bool odd = (lane & 1) != 0;
    float ox = odd ? nx2 : ex;
    float oy = odd ? ny2 : ey;
    bool sin2 = (f2 & 1) != 0, ein2 = (f2 & 2) != 0;
    bool vj = odd ? ein2 : (sin2 != ein2);
    vj = vj && (lane < 2 * K);
    // last = cummax(valid ? j : -1): inclusive prefix max
    int idx = vj ? lane : -1;
#pragma unroll
    for (int off = 1; off < 64; off <<= 1) {
        int o = __shfl_up(idx, off, 64);
        if (lane >= off && o > idx) idx = o;
    }
    unsigned long long bal = __ballot(vj);
    int firstv = (int)__ffsll(bal) - 1;   // argmax(valid) = first true
    int gi = (idx >= 0) ? idx : firstv;
    float gx = __shfl(ox, gi, 64);
    float gy = __shfl(oy, gi, 64);
    if (bal == 0ULL) { gx = 0.f; gy = 0.f; }
    x = gx; y = gy;
}

__global__ __launch_bounds__(64) void iou_row_kernel(
    const float* __restrict__ output, const int* __restrict__ mask,
    const int* __restrict__ ind, const float* __restrict__ target,
    float* __restrict__ rowSl1, float* __restrict__ rowLi)
{
    const int row  = blockIdx.x;     // 0 .. 1023
    const int b    = row >> 6;       // K = 64 rows per batch
    const int lane = threadIdx.x;    // block = 1 wave

    const int idx = ind[row];
    float x0v = 0.f, y0v = 0.f, x1v = 0.f, y1v = 0.f, termv = 0.f;
    if (lane < 18) {
        float p = output[(size_t)(b * 18 + lane) * 65536 + idx];
        float t = target[row * 18 + lane];
        float d = p - t, ad = fabsf(d);
        termv = (ad < 1.f) ? 0.5f * d * d : (ad - 0.5f);
        float ang = (float)lane * ((float)M_PI / 18.0f);
        float c = cosf(ang), s = sinf(ang);
        x0v = p * c; y0v = p * s;
        x1v = t * c; y1v = t * s;
    }

    // smooth-L1 mean in sequential order (matches np)
    float sl1 = 0.f;
#pragma unroll
    for (int k = 0; k < 18; ++k) sl1 += __shfl(termv, k, 64);
    sl1 = sl1 / 18.0f;

    float ax0,ay0,ax1,ay1,ax2,ay2,ax3,ay3;
    float bx0,by0,bx1,by1,bx2,by2,bx3,by3;
    min_area_rect(x0v, y0v, lane, ax0,ay0,ax1,ay1,ax2,ay2,ax3,ay3);
    min_area_rect(x1v, y1v, lane, bx0,by0,bx1,by1,bx2,by2,bx3,by3);

    float areaA = shoe4(ax0,ay0,ax1,ay1,ax2,ay2,ax3,ay3);
    float areaB = shoe4(bx0,by0,bx1,by1,bx2,by2,bx3,by3);

    // clip poly A by poly B's 4 half-planes (lane-parallel, literal reference)
    int s3 = lane & 3;
    float px = (s3 == 0) ? ax0 : (s3 == 1) ? ax1 : (s3 == 2) ? ax2 : ax3;
    float py = (s3 == 0) ? ay0 : (s3 == 1) ? ay1 : (s3 == 2) ? ay2 : ay3;
    clip_step<4 >(px, py, bx0, by0, bx1, by1, lane);
    clip_step<8 >(px, py, bx1, by1, bx2, by2, lane);
    clip_step<16>(px, py, bx2, by2, bx3, by3, lane);
    clip_step<32>(px, py, bx3, by3, bx0, by0, lane);

    // shoelace over the 64-slot polygon
    float xn = __shfl(px, (lane + 1) & 63, 64);
    float yn = __shfl(py, (lane + 1) & 63, 64);
    float term = px * yn - py * xn;
#pragma unroll
    for (int off = 1; off < 64; off <<= 1) term += __shfl_xor(term, off, 64);
    float inter = 0.5f * fabsf(term);

    float uni = areaA + areaB - inter;
    float iou = inter / fmaxf(uni, 1e-12f);

    if (lane == 0) {
        float mf = (float)mask[row];
        float alpha = -logf(fabsf(iou) + EPS_F);
        float li = alpha * sl1 / (fabsf(sl1) + EPS_F);
        rowSl1[row] = sl1 * mf;
        rowLi[row]  = li * mf;
    }
}

__global__ __launch_bounds__(256) void iou_reduce_kernel(
    const float* __restrict__ rowSl1, const float* __restrict__ rowLi,
    const int* __restrict__ mask, float* __restrict__ out)
{
    __shared__ float s1[256], s2[256], s3[256];
    const int tid = threadIdx.x;
    float a = 0.f, c = 0.f, msum = 0.f;
    for (int i = tid; i < 1024; i += 256) {
        a += rowSl1[i];
        c += rowLi[i];
        msum += (float)mask[i];
    }
    s1[tid] = a; s2[tid] = c; s3[tid] = msum;
    __syncthreads();
    for (int off = 128; off > 0; off >>= 1) {
        if (tid < off) {
            s1[tid] += s1[tid + off];
            s2[tid] += s2[tid + off];
            s3[tid] += s3[tid + off];
        }
        __syncthreads();
    }
    if (tid == 0) {
        float cnt = fmaxf(s3[0], 1.0f);
        out[0] = s1[0] / cnt;
        out[1] = s2[0] / cnt;
    }
}

extern "C" void kernel_launch(void* const* d_in, const int* in_sizes, int n_in,
                              void* d_out, int out_size, void* d_ws, size_t ws_size,
                              hipStream_t stream) {
    const float* output = (const float*)d_in[0];
    const int*   mask   = (const int*)d_in[1];
    const int*   ind    = (const int*)d_in[2];
    const float* target = (const float*)d_in[3];
    float* out    = (float*)d_out;
    float* rowSl1 = (float*)d_ws;
    float* rowLi  = rowSl1 + 1024;

    iou_row_kernel<<<1024, 64, 0, stream>>>(output, mask, ind, target, rowSl1, rowLi);
    iou_reduce_kernel<<<1, 256, 0, stream>>>(rowSl1, rowLi, mask, out);
}